// Round 4
// baseline (144.748 us; speedup 1.0000x reference)
//
#include <hip/hip_runtime.h>
#include <math.h>

#define QN 8
#define NDIMS 2
#define LATENT 64
#define OUTC 32     // Q + Q + Q*NDIMS
#define IT 16       // i-rows per thread in pair kernel

// ---------------------------------------------------------------------------
// Phase 1: per-point feature MLP + derived quantities.
// One point per thread, one wave per block (64 blocks -> ~1 wave/CU).
// Weights (9 KB) staged into LDS once per block with coalesced float4 loads;
// compute reads them as broadcast ds_read_b128 (all lanes same address ->
// no bank conflicts, ~12cyc throughput each, deeply pipelined by unroll).
// This removes the serialized s_load/K$-latency chain that made r0/r3 ~63us.
// Store per point (32 floats):
//   [0:8)   u[q]   = w*sqrt(s)*2^0.25     (so uA*uB = wA*wB*sqrt(2 sA sB))
//   [8:16)  ssq[q] = s*s
//   [16:24) cos(2*pi*phi[q])
//   [24:32) sin(2*pi*phi[q])
// ---------------------------------------------------------------------------
__global__ __launch_bounds__(64) void feat_kernel(
    const float* __restrict__ x, const float* __restrict__ y, int n,
    const float* __restrict__ W1, const float* __restrict__ b1,
    const float* __restrict__ W2, const float* __restrict__ b2,
    float* __restrict__ featX, float* __restrict__ featY)
{
    __shared__ __align__(16) float w1s[2 * LATENT];     // 128 f
    __shared__ __align__(16) float b1s[LATENT];         // 64 f
    __shared__ __align__(16) float w2s[OUTC * LATENT];  // 2048 f
    __shared__ __align__(16) float b2s[OUTC];           // 32 f

    const int tid  = threadIdx.x;
    const int gp   = blockIdx.x * 64 + tid;
    const int npts = 2 * n;

    // ---- stage weights to LDS (all threads participate; sync before use) ---
    {
        const float4* s = (const float4*)W2;
        float4*       d = (float4*)w2s;
        #pragma unroll
        for (int i = 0; i < (OUTC * LATENT) / 4 / 64; ++i)   // 8 per thread
            d[tid + 64 * i] = s[tid + 64 * i];
        if (tid < 32)      ((float4*)w1s)[tid]      = ((const float4*)W1)[tid];
        else if (tid < 48) ((float4*)b1s)[tid - 32] = ((const float4*)b1)[tid - 32];
        else if (tid < 56) ((float4*)b2s)[tid - 48] = ((const float4*)b2)[tid - 48];
    }
    __syncthreads();
    if (gp >= npts) return;

    const float* p = (gp < n) ? (x + 2 * gp) : (y + 2 * (gp - n));
    float p0 = p[0], p1 = p[1];

    const float kScale = 1.0507009873554804934193349852946f;
    const float kAlpha = 1.6732632423543772848170429916717f;

    // ---- h = selu(W1 p + b1), weights via broadcast LDS float4 reads ------
    float h[LATENT];
    #pragma unroll
    for (int k = 0; k < LATENT; k += 4) {
        float4 wa = ((const float4*)w1s)[k / 2];       // W1[2k .. 2k+3]
        float4 wb = ((const float4*)w1s)[k / 2 + 1];   // W1[2k+4 .. 2k+7]
        float4 bb = ((const float4*)b1s)[k / 4];       // b1[k .. k+3]
        float z0 = fmaf(wa.x, p0, fmaf(wa.y, p1, bb.x));
        float z1 = fmaf(wa.z, p0, fmaf(wa.w, p1, bb.y));
        float z2 = fmaf(wb.x, p0, fmaf(wb.y, p1, bb.z));
        float z3 = fmaf(wb.z, p0, fmaf(wb.w, p1, bb.w));
        h[k + 0] = kScale * (z0 > 0.f ? z0 : kAlpha * (__expf(z0) - 1.f));
        h[k + 1] = kScale * (z1 > 0.f ? z1 : kAlpha * (__expf(z1) - 1.f));
        h[k + 2] = kScale * (z2 > 0.f ? z2 : kAlpha * (__expf(z2) - 1.f));
        h[k + 3] = kScale * (z3 > 0.f ? z3 : kAlpha * (__expf(z3) - 1.f));
    }

    // ---- a = softplus(W2 h + b2), broadcast ds_read_b128 of W2 rows -------
    float a[OUTC];
    #pragma unroll
    for (int o = 0; o < OUTC; ++o) {
        const float4* w = (const float4*)(w2s + o * LATENT);   // 16 float4
        float z0 = b2s[o], z1 = 0.f, z2 = 0.f, z3 = 0.f;
        #pragma unroll
        for (int c = 0; c < LATENT / 16; ++c) {
            float4 w0 = w[4 * c + 0];
            float4 w1v = w[4 * c + 1];
            float4 w2v = w[4 * c + 2];
            float4 w3 = w[4 * c + 3];
            int k = 16 * c;
            z0 = fmaf(w0.x,  h[k+0],  fmaf(w0.y,  h[k+1],  fmaf(w0.z,  h[k+2],  fmaf(w0.w,  h[k+3],  z0))));
            z1 = fmaf(w1v.x, h[k+4],  fmaf(w1v.y, h[k+5],  fmaf(w1v.z, h[k+6],  fmaf(w1v.w, h[k+7],  z1))));
            z2 = fmaf(w2v.x, h[k+8],  fmaf(w2v.y, h[k+9],  fmaf(w2v.z, h[k+10], fmaf(w2v.w, h[k+11], z2))));
            z3 = fmaf(w3.x,  h[k+12], fmaf(w3.y,  h[k+13], fmaf(w3.z,  h[k+14], fmaf(w3.w,  h[k+15], z3))));
        }
        float z = (z0 + z1) + (z2 + z3);
        // stable softplus: max(z,0) + log(1 + exp(-|z|)), fast intrinsics
        a[o] = fmaxf(z, 0.f) + __logf(1.f + __expf(-fabsf(z)));
    }

    // ---- derived per-q features, vectorized stores (4x float4 per point) --
    float4 uo, so, co, sno;
    float* uop = &uo.x; float* sop = &so.x; float* cop = &co.x; float* snp = &sno.x;
    float* fo = (gp < n) ? (featX + 32 * gp) : (featY + 32 * (gp - n));
    const float TWO_PI  = 6.283185307179586f;
    const float ROOT4_2 = 1.18920711500272107f;   // 2^(1/4)
    #pragma unroll
    for (int qq = 0; qq < 2; ++qq) {
        #pragma unroll
        for (int r = 0; r < 4; ++r) {
            int q = 4 * qq + r;
            float w  = a[q];
            float s  = a[QN + q];
            float f0 = a[2 * QN + 2 * q];
            float f1 = a[2 * QN + 2 * q + 1];
            float phi = fmaf(f0, p0, f1 * p1);
            float rr  = phi - floorf(phi);        // reduce to [0,1) revolutions
            float ang = TWO_PI * rr;
            uop[r] = w * sqrtf(s) * ROOT4_2;
            sop[r] = s * s;
            cop[r] = __cosf(ang);
            snp[r] = __sinf(ang);
        }
        *(float4*)(fo + 4 * qq)          = uo;
        *(float4*)(fo + QN + 4 * qq)     = so;
        *(float4*)(fo + 2 * QN + 4 * qq) = co;
        *(float4*)(fo + 3 * QN + 4 * qq) = sno;
    }
}

// ---------------------------------------------------------------------------
// Phase 2: pairwise kernel — UNCHANGED (clean differential; ~2-3 us, near
// the 16.8MB / 6.3TBps write floor).
// out[i,j] = sum_q uA*uB/s2 * exp(-d2/s2) * (cA*cB + snA*snB),  s2 = ssqA+ssqB
// ---------------------------------------------------------------------------
__global__ __launch_bounds__(256) void pair_kernel(
    const float* __restrict__ x, const float* __restrict__ y, int n,
    const float* __restrict__ fA, const float* __restrict__ fB,
    float* __restrict__ out)
{
    int j = blockIdx.x * 256 + threadIdx.x;
    if (j >= n) return;
    int i0 = blockIdx.y * IT;

    float uB[QN], ssB[QN], cB[QN], snB[QN];
    const float* fb = fB + 32 * j;
    #pragma unroll
    for (int q = 0; q < QN; ++q) {
        uB[q]  = fb[q];
        ssB[q] = fb[QN + q];
        cB[q]  = fb[2 * QN + q];
        snB[q] = fb[3 * QN + q];
    }
    float y0 = y[2 * j], y1 = y[2 * j + 1];

    #pragma unroll 4
    for (int ii = 0; ii < IT; ++ii) {
        int i = i0 + ii;
        if (i >= n) break;
        const float* fa = fA + 32 * i;           // wave-uniform -> s_load
        float dx = x[2 * i]     - y0;
        float dy = x[2 * i + 1] - y1;
        float d2 = fmaf(dx, dx, dy * dy);
        float acc = 0.f;
        #pragma unroll
        for (int q = 0; q < QN; ++q) {
            float s2  = fa[QN + q] + ssB[q];
            float inv = __builtin_amdgcn_rcpf(s2);
            float e   = __expf(-d2 * inv);
            float g   = fa[q] * uB[q] * inv * e;
            float c   = fmaf(fa[2 * QN + q], cB[q], fa[3 * QN + q] * snB[q]);
            acc = fmaf(g, c, acc);
        }
        out[(long)i * n + j] = acc;
    }
}

extern "C" void kernel_launch(void* const* d_in, const int* in_sizes, int n_in,
                              void* d_out, int out_size, void* d_ws, size_t ws_size,
                              hipStream_t stream)
{
    const float* x  = (const float*)d_in[0];
    const float* y  = (const float*)d_in[1];
    const float* W1 = (const float*)d_in[2];
    const float* b1 = (const float*)d_in[3];
    const float* W2 = (const float*)d_in[4];
    const float* b2 = (const float*)d_in[5];
    float* out = (float*)d_out;

    int n = in_sizes[0] / NDIMS;     // 2048

    float* featX = (float*)d_ws;
    float* featY = featX + (size_t)n * 32;

    int npts = 2 * n;
    hipLaunchKernelGGL(feat_kernel, dim3((npts + 63) / 64), dim3(64), 0, stream,
                       x, y, n, W1, b1, W2, b2, featX, featY);

    dim3 grid((n + 255) / 256, (n + IT - 1) / IT);
    hipLaunchKernelGGL(pair_kernel, grid, dim3(256), 0, stream,
                       x, y, n, featX, featY, out);
}

// Round 5
// 33.463 us; speedup vs baseline: 4.3256x; 4.3256x over previous
//
#include <hip/hip_runtime.h>
#include <math.h>

#define QN 8
#define NDIMS 2
#define LATENT 64
#define OUTC 32     // Q + Q + Q*NDIMS
#define IT 16       // i-rows per thread in pair kernel

// ---------------------------------------------------------------------------
// Phase 1: feature MLP, ONE THREAD PER (point, output-unit).
// 4096 points x 32 outputs = 131072 threads = 2048 waves (8 waves/CU) -> all
// latency (K$/L1/L2) hidden by occupancy. No LDS, no barriers, no spills:
// the hidden layer is recomputed per-lane in chunks of 16 interleaved with
// the W2 dot, so peak live state ~ 16 h + 4 float4 + 4 acc  (~60 VGPR).
// After softplus, lane o of each half-wave holds a[o] for its point; the
// derived per-q features are assembled with 4 intra-wave shuffles and
// stored by lanes (l&31) < 8.
// Store per point (32 floats):
//   [0:8)   u[q]   = w*sqrt(s)*2^0.25     (so uA*uB = wA*wB*sqrt(2 sA sB))
//   [8:16)  ssq[q] = s*s
//   [16:24) cos(2*pi*phi[q])
//   [24:32) sin(2*pi*phi[q])
// ---------------------------------------------------------------------------
__global__ __launch_bounds__(256) void feat_kernel(
    const float* __restrict__ x, const float* __restrict__ y, int n,
    const float* __restrict__ W1, const float* __restrict__ b1,
    const float* __restrict__ W2, const float* __restrict__ b2,
    float* __restrict__ featX, float* __restrict__ featY)
{
    const int t    = blockIdx.x * 256 + threadIdx.x;
    const int pt   = t >> 5;                 // point index (2 points per wave)
    const int o    = t & 31;                 // output unit for this lane
    const int npts = 2 * n;
    if (pt >= npts) return;

    const float* p = (pt < n) ? (x + 2 * pt) : (y + 2 * (pt - n));
    float p0 = p[0], p1 = p[1];

    const float kScale = 1.0507009873554804934193349852946f;
    const float kAlpha = 1.6732632423543772848170429916717f;

    // z = W2[o,:] . selu(W1 p + b1) + b2[o], hidden chunked 16-at-a-time.
    // W1/b1: wave-uniform -> s_load (latency hidden, 8 waves/CU).
    // W2 row o: per-lane float4 vector loads, L1-hot (8 KB total).
    const float4* w2v = (const float4*)(W2 + o * LATENT);
    float z0 = b2[o], z1 = 0.f, z2 = 0.f, z3 = 0.f;
    #pragma unroll
    for (int c = 0; c < LATENT / 16; ++c) {
        float hb[16];
        #pragma unroll
        for (int r = 0; r < 16; ++r) {
            int k = 16 * c + r;
            float zz = fmaf(W1[2 * k], p0, fmaf(W1[2 * k + 1], p1, b1[k]));
            hb[r] = kScale * (zz > 0.f ? zz : kAlpha * (__expf(zz) - 1.f));
        }
        float4 w0 = w2v[4 * c + 0];
        float4 w1v = w2v[4 * c + 1];
        float4 w2q = w2v[4 * c + 2];
        float4 w3 = w2v[4 * c + 3];
        z0 = fmaf(w0.x,  hb[0],  fmaf(w0.y,  hb[1],  fmaf(w0.z,  hb[2],  fmaf(w0.w,  hb[3],  z0))));
        z1 = fmaf(w1v.x, hb[4],  fmaf(w1v.y, hb[5],  fmaf(w1v.z, hb[6],  fmaf(w1v.w, hb[7],  z1))));
        z2 = fmaf(w2q.x, hb[8],  fmaf(w2q.y, hb[9],  fmaf(w2q.z, hb[10], fmaf(w2q.w, hb[11], z2))));
        z3 = fmaf(w3.x,  hb[12], fmaf(w3.y,  hb[13], fmaf(w3.z,  hb[14], fmaf(w3.w,  hb[15], z3))));
    }
    float z = (z0 + z1) + (z2 + z3);
    // stable softplus: max(z,0) + log(1 + exp(-|z|))
    float av = fmaxf(z, 0.f) + __logf(1.f + __expf(-fabsf(z)));

    // ---- stage C: gather (w, s, f0, f1) for q = lane&7 via shuffles -------
    const int lane = threadIdx.x & 63;
    const int base = lane & 32;               // half-wave owning this point
    const int q    = lane & 7;
    float w_ = __shfl(av, base + q, 64);
    float s_ = __shfl(av, base + 8 + q, 64);
    float f0 = __shfl(av, base + 16 + 2 * q, 64);
    float f1 = __shfl(av, base + 17 + 2 * q, 64);

    if ((lane & 31) < 8) {
        const float TWO_PI  = 6.283185307179586f;
        const float ROOT4_2 = 1.18920711500272107f;   // 2^(1/4)
        float phi = fmaf(f0, p0, f1 * p1);
        float rr  = phi - floorf(phi);        // reduce to [0,1) revolutions
        float ang = TWO_PI * rr;
        float* fo = (pt < n) ? (featX + 32 * pt) : (featY + 32 * (pt - n));
        fo[q]          = w_ * sqrtf(s_) * ROOT4_2;
        fo[QN + q]     = s_ * s_;
        fo[2 * QN + q] = __cosf(ang);
        fo[3 * QN + q] = __sinf(ang);
    }
}

// ---------------------------------------------------------------------------
// Phase 2: pairwise kernel — UNCHANGED (clean differential; measured ~2 us,
// near the 16.8MB / 6.3TBps write floor).
// out[i,j] = sum_q uA*uB/s2 * exp(-d2/s2) * (cA*cB + snA*snB),  s2 = ssqA+ssqB
// ---------------------------------------------------------------------------
__global__ __launch_bounds__(256) void pair_kernel(
    const float* __restrict__ x, const float* __restrict__ y, int n,
    const float* __restrict__ fA, const float* __restrict__ fB,
    float* __restrict__ out)
{
    int j = blockIdx.x * 256 + threadIdx.x;
    if (j >= n) return;
    int i0 = blockIdx.y * IT;

    float uB[QN], ssB[QN], cB[QN], snB[QN];
    const float* fb = fB + 32 * j;
    #pragma unroll
    for (int q = 0; q < QN; ++q) {
        uB[q]  = fb[q];
        ssB[q] = fb[QN + q];
        cB[q]  = fb[2 * QN + q];
        snB[q] = fb[3 * QN + q];
    }
    float y0 = y[2 * j], y1 = y[2 * j + 1];

    #pragma unroll 4
    for (int ii = 0; ii < IT; ++ii) {
        int i = i0 + ii;
        if (i >= n) break;
        const float* fa = fA + 32 * i;           // wave-uniform -> s_load
        float dx = x[2 * i]     - y0;
        float dy = x[2 * i + 1] - y1;
        float d2 = fmaf(dx, dx, dy * dy);
        float acc = 0.f;
        #pragma unroll
        for (int q = 0; q < QN; ++q) {
            float s2  = fa[QN + q] + ssB[q];
            float inv = __builtin_amdgcn_rcpf(s2);
            float e   = __expf(-d2 * inv);
            float g   = fa[q] * uB[q] * inv * e;
            float c   = fmaf(fa[2 * QN + q], cB[q], fa[3 * QN + q] * snB[q]);
            acc = fmaf(g, c, acc);
        }
        out[(long)i * n + j] = acc;
    }
}

extern "C" void kernel_launch(void* const* d_in, const int* in_sizes, int n_in,
                              void* d_out, int out_size, void* d_ws, size_t ws_size,
                              hipStream_t stream)
{
    const float* x  = (const float*)d_in[0];
    const float* y  = (const float*)d_in[1];
    const float* W1 = (const float*)d_in[2];
    const float* b1 = (const float*)d_in[3];
    const float* W2 = (const float*)d_in[4];
    const float* b2 = (const float*)d_in[5];
    float* out = (float*)d_out;

    int n = in_sizes[0] / NDIMS;     // 2048

    float* featX = (float*)d_ws;
    float* featY = featX + (size_t)n * 32;

    int npts = 2 * n;
    int featThreads = npts * OUTC;                    // one thread per (pt, o)
    hipLaunchKernelGGL(feat_kernel, dim3((featThreads + 255) / 256), dim3(256), 0, stream,
                       x, y, n, W1, b1, W2, b2, featX, featY);

    dim3 grid((n + 255) / 256, (n + IT - 1) / IT);
    hipLaunchKernelGGL(pair_kernel, grid, dim3(256), 0, stream,
                       x, y, n, featX, featY, out);
}

// Round 6
// 27.913 us; speedup vs baseline: 5.1857x; 1.1988x over previous
//
#include <hip/hip_runtime.h>
#include <math.h>

#define QN 8
#define NDIMS 2
#define LATENT 64
#define OUTC 32     // Q + Q + Q*NDIMS
#define IT 16       // i-rows per block tile in pair kernel

// ---------------------------------------------------------------------------
// Phase 1: feature MLP — BYTE-IDENTICAL to round 5 (clean differential).
// One thread per (point, output-unit); 2048 waves; no LDS/barriers/spills.
// ---------------------------------------------------------------------------
__global__ __launch_bounds__(256) void feat_kernel(
    const float* __restrict__ x, const float* __restrict__ y, int n,
    const float* __restrict__ W1, const float* __restrict__ b1,
    const float* __restrict__ W2, const float* __restrict__ b2,
    float* __restrict__ featX, float* __restrict__ featY)
{
    const int t    = blockIdx.x * 256 + threadIdx.x;
    const int pt   = t >> 5;                 // point index (2 points per wave)
    const int o    = t & 31;                 // output unit for this lane
    const int npts = 2 * n;
    if (pt >= npts) return;

    const float* p = (pt < n) ? (x + 2 * pt) : (y + 2 * (pt - n));
    float p0 = p[0], p1 = p[1];

    const float kScale = 1.0507009873554804934193349852946f;
    const float kAlpha = 1.6732632423543772848170429916717f;

    const float4* w2v = (const float4*)(W2 + o * LATENT);
    float z0 = b2[o], z1 = 0.f, z2 = 0.f, z3 = 0.f;
    #pragma unroll
    for (int c = 0; c < LATENT / 16; ++c) {
        float hb[16];
        #pragma unroll
        for (int r = 0; r < 16; ++r) {
            int k = 16 * c + r;
            float zz = fmaf(W1[2 * k], p0, fmaf(W1[2 * k + 1], p1, b1[k]));
            hb[r] = kScale * (zz > 0.f ? zz : kAlpha * (__expf(zz) - 1.f));
        }
        float4 w0 = w2v[4 * c + 0];
        float4 w1v = w2v[4 * c + 1];
        float4 w2q = w2v[4 * c + 2];
        float4 w3 = w2v[4 * c + 3];
        z0 = fmaf(w0.x,  hb[0],  fmaf(w0.y,  hb[1],  fmaf(w0.z,  hb[2],  fmaf(w0.w,  hb[3],  z0))));
        z1 = fmaf(w1v.x, hb[4],  fmaf(w1v.y, hb[5],  fmaf(w1v.z, hb[6],  fmaf(w1v.w, hb[7],  z1))));
        z2 = fmaf(w2q.x, hb[8],  fmaf(w2q.y, hb[9],  fmaf(w2q.z, hb[10], fmaf(w2q.w, hb[11], z2))));
        z3 = fmaf(w3.x,  hb[12], fmaf(w3.y,  hb[13], fmaf(w3.z,  hb[14], fmaf(w3.w,  hb[15], z3))));
    }
    float z = (z0 + z1) + (z2 + z3);
    float av = fmaxf(z, 0.f) + __logf(1.f + __expf(-fabsf(z)));

    const int lane = threadIdx.x & 63;
    const int base = lane & 32;               // half-wave owning this point
    const int q    = lane & 7;
    float w_ = __shfl(av, base + q, 64);
    float s_ = __shfl(av, base + 8 + q, 64);
    float f0 = __shfl(av, base + 16 + 2 * q, 64);
    float f1 = __shfl(av, base + 17 + 2 * q, 64);

    if ((lane & 31) < 8) {
        const float TWO_PI  = 6.283185307179586f;
        const float ROOT4_2 = 1.18920711500272107f;   // 2^(1/4)
        float phi = fmaf(f0, p0, f1 * p1);
        float rr  = phi - floorf(phi);
        float ang = TWO_PI * rr;
        float* fo = (pt < n) ? (featX + 32 * pt) : (featY + 32 * (pt - n));
        fo[q]          = w_ * sqrtf(s_) * ROOT4_2;
        fo[QN + q]     = s_ * s_;
        fo[2 * QN + q] = __cosf(ang);
        fo[3 * QN + q] = __sinf(ang);
    }
}

// ---------------------------------------------------------------------------
// Phase 2: pairwise kernel — REWRITTEN.
//  * i-tile features (2 KB) + x-coords cooperatively staged to LDS with
//    coalesced dwordx4, consumed as broadcast ds_read_b128 (no scalar-path
//    serialization, no SGPR pressure).
//  * fb loaded as 8 explicit float4 into named regs (static indices only).
//  * d2 pre-scaled by log2(e) once per i; v_exp (exp2) directly per q.
// out[i,j] = sum_q uA*uB/s2 * exp(-d2/s2) * (cA*cB + snA*snB),  s2 = ssqA+ssqB
// ---------------------------------------------------------------------------
__global__ __launch_bounds__(256) void pair_kernel(
    const float* __restrict__ x, const float* __restrict__ y, int n,
    const float* __restrict__ fA, const float* __restrict__ fB,
    float* __restrict__ out)
{
    __shared__ __align__(16) float faS[IT * 32];   // 2 KB: 32 feats per i
    __shared__ __align__(16) float xaS[IT * 2];    // (x0,x1) per i

    const int tid = threadIdx.x;
    const int j   = blockIdx.x * 256 + tid;
    const int i0  = blockIdx.y * IT;

    // ---- cooperative stage of the i-tile (coalesced float4) ----
    if (tid < IT * 8) {                                 // 128 float4s of fA
        ((float4*)faS)[tid] = ((const float4*)(fA + (size_t)i0 * 32))[tid];
    } else if (tid < IT * 8 + IT / 2) {                 // 8 float4s of x
        ((float4*)xaS)[tid - IT * 8] = ((const float4*)(x + 2 * i0))[tid - IT * 8];
    }
    __syncthreads();

    if (j >= n) return;     // no barriers after this point

    // ---- fb into named registers via 8 dwordx4 ----
    const float4* fb4 = (const float4*)(fB + 32 * j);
    float4 fu0 = fb4[0], fu1 = fb4[1];
    float4 fs0 = fb4[2], fs1 = fb4[3];
    float4 fc0 = fb4[4], fc1 = fb4[5];
    float4 fn0 = fb4[6], fn1 = fb4[7];
    float uB[QN]  = {fu0.x,fu0.y,fu0.z,fu0.w, fu1.x,fu1.y,fu1.z,fu1.w};
    float ssB[QN] = {fs0.x,fs0.y,fs0.z,fs0.w, fs1.x,fs1.y,fs1.z,fs1.w};
    float cB[QN]  = {fc0.x,fc0.y,fc0.z,fc0.w, fc1.x,fc1.y,fc1.z,fc1.w};
    float snB[QN] = {fn0.x,fn0.y,fn0.z,fn0.w, fn1.x,fn1.y,fn1.z,fn1.w};

    float2 yv = *(const float2*)(y + 2 * j);
    const float LOG2E = 1.4426950408889634f;

    #pragma unroll 2
    for (int ii = 0; ii < IT; ++ii) {
        int i = i0 + ii;
        if (i >= n) break;

        // broadcast ds_read_b128 of this i's features (all lanes same addr)
        const float4* fa4 = (const float4*)(faS + ii * 32);
        float4 au0 = fa4[0], au1 = fa4[1];
        float4 as0 = fa4[2], as1 = fa4[3];
        float4 ac0 = fa4[4], ac1 = fa4[5];
        float4 an0 = fa4[6], an1 = fa4[7];
        float uA[QN]  = {au0.x,au0.y,au0.z,au0.w, au1.x,au1.y,au1.z,au1.w};
        float ssA[QN] = {as0.x,as0.y,as0.z,as0.w, as1.x,as1.y,as1.z,as1.w};
        float cA[QN]  = {ac0.x,ac0.y,ac0.z,ac0.w, ac1.x,ac1.y,ac1.z,ac1.w};
        float snA[QN] = {an0.x,an0.y,an0.z,an0.w, an1.x,an1.y,an1.z,an1.w};

        float dx  = xaS[2 * ii]     - yv.x;
        float dy  = xaS[2 * ii + 1] - yv.y;
        float d2l = fmaf(dx, dx, dy * dy) * LOG2E;   // d2 * log2(e)

        float acc = 0.f;
        #pragma unroll
        for (int q = 0; q < QN; ++q) {
            float s2  = ssA[q] + ssB[q];
            float inv = __builtin_amdgcn_rcpf(s2);
            float e   = __builtin_amdgcn_exp2f(-d2l * inv);   // exp(-d2/s2)
            float g   = uA[q] * uB[q] * inv * e;
            float c   = fmaf(cA[q], cB[q], snA[q] * snB[q]);
            acc = fmaf(g, c, acc);
        }
        out[(long)i * n + j] = acc;
    }
}

extern "C" void kernel_launch(void* const* d_in, const int* in_sizes, int n_in,
                              void* d_out, int out_size, void* d_ws, size_t ws_size,
                              hipStream_t stream)
{
    const float* x  = (const float*)d_in[0];
    const float* y  = (const float*)d_in[1];
    const float* W1 = (const float*)d_in[2];
    const float* b1 = (const float*)d_in[3];
    const float* W2 = (const float*)d_in[4];
    const float* b2 = (const float*)d_in[5];
    float* out = (float*)d_out;

    int n = in_sizes[0] / NDIMS;     // 2048

    float* featX = (float*)d_ws;
    float* featY = featX + (size_t)n * 32;

    int npts = 2 * n;
    int featThreads = npts * OUTC;                    // one thread per (pt, o)
    hipLaunchKernelGGL(feat_kernel, dim3((featThreads + 255) / 256), dim3(256), 0, stream,
                       x, y, n, W1, b1, W2, b2, featX, featY);

    dim3 grid((n + 255) / 256, (n + IT - 1) / IT);
    hipLaunchKernelGGL(pair_kernel, grid, dim3(256), 0, stream,
                       x, y, n, featX, featY, out);
}